// Round 5
// baseline (133.729 us; speedup 1.0000x reference)
//
#include <hip/hip_runtime.h>

#define EPS_ 1.1920928955078125e-07f
#define SCALE_ 0.17677669529663687f   // 1/sqrt(32)

typedef __attribute__((ext_vector_type(8))) short s8b;     // 8 bf16 (16B)
typedef __attribute__((ext_vector_type(4))) float f32x4;   // MFMA acc

static __device__ __forceinline__ unsigned short f2bf(float f) {
  unsigned int u = __float_as_uint(f);
  unsigned int r = (u + 0x7fffu + ((u >> 16) & 1u)) >> 16;   // RNE
  return (unsigned short)r;
}
static __device__ __forceinline__ float b2fs(short h) {
  return __uint_as_float(((unsigned int)(unsigned short)h) << 16);
}
static __device__ __forceinline__ int S_(int c) {        // NATTEN window start (cell grid)
  return (c < 3) ? 0 : ((c > 28) ? 25 : (c - 3));
}

// ---------------------------------------------------------------------------
// wpack: conv weights -> wb [9][4][128oc][32ic] bf16; wnq/wnk = proj_w*norm_w
// ---------------------------------------------------------------------------
__global__ __launch_bounds__(256) void wpack_k(
    const float* __restrict__ cw, const float* __restrict__ qw,
    const float* __restrict__ nqw, const float* __restrict__ kw,
    const float* __restrict__ nkw, unsigned short* __restrict__ wb,
    unsigned short* __restrict__ wnq, unsigned short* __restrict__ wnk) {
  int idx = blockIdx.x * 256 + threadIdx.x;
  if (idx < 147456) {
    int i32 = idx & 31, r = idx >> 5;
    int oc = r & 127, r2 = r >> 7;
    int kc = r2 & 3, t = r2 >> 2;
    wb[idx] = f2bf(cw[oc * 1152 + (kc * 32 + i32) * 9 + t]);
  } else if (idx < 163840) {
    int j = idx - 147456;
    wnq[j] = f2bf(qw[j] * nqw[j & 127]);
  } else if (idx < 180224) {
    int j = idx - 163840;
    wnk[j] = f2bf(kw[j] * nkw[j & 127]);
  }
}

// ---------------------------------------------------------------------------
// fused: per 8x8 output tile (grid 256, 1 blk/CU): stage q halo/k/v from fp32,
// k-rms+kproj, conv3x3 implicit GEMM, q-rms+qproj, QK^T, masked softmax,
// head-summed PV, transposed output. Weights read from global (L2-hot).
// LDS (65344B static, phase-overlaid):
//   @0     in_l [100][136] bf16 (27200)  -> qc_l [64][136] (17408)
//                                         -> a1_l @17408 [64][72] (9216)
//   @27200 kx_l/kp_l [64][136] (17408)
//   @44608 v_l  [128][72] bf16 (18432)
//   @0     o_l  [128][68] f32 (34816, after PV)
//   @63040 red[256]f32 | @64064 rs[64] | @64320 bq[128] | @64832 bk[128]
// ---------------------------------------------------------------------------
__global__ __launch_bounds__(256) void fused_k(
    const float* __restrict__ q_in, const float* __restrict__ k_in,
    const float* __restrict__ v_in, const unsigned short* __restrict__ wb,
    const unsigned short* __restrict__ wnq, const unsigned short* __restrict__ wnk,
    const float* __restrict__ qbias, const float* __restrict__ kbias,
    float* __restrict__ out) {
  __shared__ __align__(16) char smem[65344];
  unsigned short* in_l = (unsigned short*)smem;
  unsigned short* qc_l = (unsigned short*)smem;
  unsigned short* a1_l = (unsigned short*)(smem + 17408);
  unsigned short* kx_l = (unsigned short*)(smem + 27200);   // kp_l after proj
  unsigned short* v_l  = (unsigned short*)(smem + 44608);
  float* o_l   = (float*)smem;
  float* red_l = (float*)(smem + 63040);
  float* rs_l  = (float*)(smem + 64064);
  float* bq_l  = (float*)(smem + 64320);
  float* bk_l  = (float*)(smem + 64832);

  const int tid = threadIdx.x;
  const int CY = blockIdx.x >> 4, CX = blockIdx.x & 15;
  const int Y0 = CY * 8, X0 = CX * 8;
  const int w = tid >> 6, lane = tid & 63;
  const int lm = lane & 15, kg = lane >> 4;
  const int mg = w & 1, ng = w >> 1;          // (4m,2n) wave split for GEMMs

  const int sy0 = S_(2 * CY), sy1 = S_(2 * CY + 1);
  const int sx0 = S_(2 * CX), sx1 = S_(2 * CX + 1);
  const int kyb = min(sy0, 24), kxb = min(sx0, 24);
  const int oy0 = sy0 - kyb, oy1 = sy1 - kyb;
  const int ox0 = sx0 - kxb, ox1 = sx1 - kxb;

  // ---- stage: q halo (zero-padded), k window, v window; biases ----
  if (tid < 128) { bq_l[tid] = qbias[tid]; bk_l[tid] = kbias[tid]; }
  for (int i = tid; i < 12800; i += 256) {
    int c = i / 100, r = i - c * 100;
    int ry = r / 10, rx = r - ry * 10;
    int gy = Y0 - 1 + ry, gx = X0 - 1 + rx;
    float v = 0.f;
    if ((unsigned)gy < 128u && (unsigned)gx < 128u) v = q_in[c * 16384 + gy * 128 + gx];
    in_l[r * 136 + c] = f2bf(v);
  }
  for (int i = tid; i < 8192; i += 256) {
    int c = i >> 6, j = i & 63;
    int ky = j >> 3, kx = j & 7;
    kx_l[j * 136 + c] = f2bf(k_in[c * 1024 + (kyb + ky) * 32 + kxb + kx]);
  }
  for (int i = tid; i < 8192; i += 256) {
    int c = i >> 6, j = i & 63;
    int ky = j >> 3, kx = j & 7;
    v_l[c * 72 + j] = f2bf(v_in[c * 1024 + (kyb + ky) * 32 + kxb + kx]);
  }
  __syncthreads();

  // ---- k rms ----
  {
    int px = tid >> 2, t4 = tid & 3;
    float ssum = 0.f;
#pragma unroll
    for (int j = 0; j < 4; j++) {
      s8b v = *(const s8b*)&kx_l[px * 136 + t4 * 32 + j * 8];
#pragma unroll
      for (int e = 0; e < 8; e++) { float f = b2fs(v[e]); ssum += f * f; }
    }
    red_l[px * 4 + t4] = ssum;
  }
  __syncthreads();
  if (tid < 64)
    rs_l[tid] = rsqrtf((red_l[4 * tid] + red_l[4 * tid + 1] + red_l[4 * tid + 2] +
                        red_l[4 * tid + 3]) * (1.f / 128.f) + EPS_);
  __syncthreads();

  // ---- k proj: kp = kbias + rs*(wnk @ kx) ----
  {
    f32x4 ka[4][2];
#pragma unroll
    for (int a = 0; a < 4; a++)
#pragma unroll
      for (int n = 0; n < 2; n++) ka[a][n] = (f32x4){0.f, 0.f, 0.f, 0.f};
#pragma unroll
    for (int kc = 0; kc < 4; kc++) {
      s8b af[4], bf[2];
#pragma unroll
      for (int mt = 0; mt < 4; mt++)
        af[mt] = *(const s8b*)&wnk[((mg * 4 + mt) * 16 + lm) * 128 + kc * 32 + kg * 8];
#pragma unroll
      for (int nt = 0; nt < 2; nt++)
        bf[nt] = *(const s8b*)&kx_l[((ng * 2 + nt) * 16 + lm) * 136 + kc * 32 + kg * 8];
#pragma unroll
      for (int mt = 0; mt < 4; mt++)
#pragma unroll
        for (int nt = 0; nt < 2; nt++)
          ka[mt][nt] = __builtin_amdgcn_mfma_f32_16x16x32_bf16(af[mt], bf[nt], ka[mt][nt], 0, 0, 0);
    }
    __syncthreads();
#pragma unroll
    for (int mt = 0; mt < 4; mt++)
#pragma unroll
      for (int nt = 0; nt < 2; nt++)
#pragma unroll
        for (int r = 0; r < 4; r++) {
          int px = (ng * 2 + nt) * 16 + lm, c = (mg * 4 + mt) * 16 + kg * 4 + r;
          kx_l[px * 136 + c] = f2bf(bk_l[c] + rs_l[px] * ka[mt][nt][r]);
        }
  }
  __syncthreads();

  // ---- conv implicit GEMM: M=128 oc, N=64 px, K=1152 ----
  f32x4 acc[4][2];
#pragma unroll
  for (int a = 0; a < 4; a++)
#pragma unroll
    for (int n = 0; n < 2; n++) acc[a][n] = (f32x4){0.f, 0.f, 0.f, 0.f};
#pragma unroll
  for (int t = 0; t < 9; t++) {
    const int dy = t / 3, dx = t - (t / 3) * 3;
#pragma unroll
    for (int kc = 0; kc < 4; kc++) {
      const unsigned short* wp = wb + (t * 4 + kc) * 4096;
      s8b af[4], bf[2];
#pragma unroll
      for (int mt = 0; mt < 4; mt++)
        af[mt] = *(const s8b*)&wp[((mg * 4 + mt) * 16 + lm) * 32 + kg * 8];
#pragma unroll
      for (int nt = 0; nt < 2; nt++) {
        int px = (ng * 2 + nt) * 16 + lm;
        int qy = px >> 3, qx = px & 7;
        bf[nt] = *(const s8b*)&in_l[((qy + dy) * 10 + qx + dx) * 136 + kc * 32 + kg * 8];
      }
#pragma unroll
      for (int mt = 0; mt < 4; mt++)
#pragma unroll
        for (int nt = 0; nt < 2; nt++)
          acc[mt][nt] = __builtin_amdgcn_mfma_f32_16x16x32_bf16(af[mt], bf[nt], acc[mt][nt], 0, 0, 0);
    }
  }
  __syncthreads();   // in_l reads done; qc_l overlays
#pragma unroll
  for (int mt = 0; mt < 4; mt++)
#pragma unroll
    for (int nt = 0; nt < 2; nt++)
#pragma unroll
      for (int r = 0; r < 4; r++) {
        int px = (ng * 2 + nt) * 16 + lm, c = (mg * 4 + mt) * 16 + kg * 4 + r;
        qc_l[px * 136 + c] = f2bf(acc[mt][nt][r]);
      }
  __syncthreads();

  // ---- q rms ----
  {
    int px = tid >> 2, t4 = tid & 3;
    float ssum = 0.f;
#pragma unroll
    for (int j = 0; j < 4; j++) {
      s8b v = *(const s8b*)&qc_l[px * 136 + t4 * 32 + j * 8];
#pragma unroll
      for (int e = 0; e < 8; e++) { float f = b2fs(v[e]); ssum += f * f; }
    }
    red_l[px * 4 + t4] = ssum;
  }
  __syncthreads();
  if (tid < 64)
    rs_l[tid] = rsqrtf((red_l[4 * tid] + red_l[4 * tid + 1] + red_l[4 * tid + 2] +
                        red_l[4 * tid + 3]) * (1.f / 128.f) + EPS_);
  __syncthreads();

  // ---- q proj ----
  {
    f32x4 qa[4][2];
#pragma unroll
    for (int a = 0; a < 4; a++)
#pragma unroll
      for (int n = 0; n < 2; n++) qa[a][n] = (f32x4){0.f, 0.f, 0.f, 0.f};
#pragma unroll
    for (int kc = 0; kc < 4; kc++) {
      s8b af[4], bf[2];
#pragma unroll
      for (int mt = 0; mt < 4; mt++)
        af[mt] = *(const s8b*)&wnq[((mg * 4 + mt) * 16 + lm) * 128 + kc * 32 + kg * 8];
#pragma unroll
      for (int nt = 0; nt < 2; nt++)
        bf[nt] = *(const s8b*)&qc_l[((ng * 2 + nt) * 16 + lm) * 136 + kc * 32 + kg * 8];
#pragma unroll
      for (int mt = 0; mt < 4; mt++)
#pragma unroll
        for (int nt = 0; nt < 2; nt++)
          qa[mt][nt] = __builtin_amdgcn_mfma_f32_16x16x32_bf16(af[mt], bf[nt], qa[mt][nt], 0, 0, 0);
    }
    __syncthreads();
#pragma unroll
    for (int mt = 0; mt < 4; mt++)
#pragma unroll
      for (int nt = 0; nt < 2; nt++)
#pragma unroll
        for (int r = 0; r < 4; r++) {
          int px = (ng * 2 + nt) * 16 + lm, c = (mg * 4 + mt) * 16 + kg * 4 + r;
          qc_l[px * 136 + c] = f2bf(bq_l[c] + rs_l[px] * qa[mt][nt][r]);
        }
  }
  __syncthreads();

  // ---- QK^T (head = wave) ----
  const int h = w;
  f32x4 lg[4][4];
  {
    s8b qa[4], kb[4];
#pragma unroll
    for (int mt = 0; mt < 4; mt++)
      qa[mt] = *(const s8b*)&qc_l[(mt * 16 + lm) * 136 + h * 32 + kg * 8];
#pragma unroll
    for (int nt = 0; nt < 4; nt++)
      kb[nt] = *(const s8b*)&kx_l[(nt * 16 + lm) * 136 + h * 32 + kg * 8];
#pragma unroll
    for (int mt = 0; mt < 4; mt++)
#pragma unroll
      for (int nt = 0; nt < 4; nt++)
        lg[mt][nt] = __builtin_amdgcn_mfma_f32_16x16x32_bf16(
            qa[mt], kb[nt], (f32x4){0.f, 0.f, 0.f, 0.f}, 0, 0, 0);
  }

  // ---- masked softmax (per head), pack P to bf16 pairs in regs ----
  unsigned int pk[4][4][2];
  const int kyA = lm >> 3, kxq = lm & 7;
  const bool kxv0 = (unsigned)(kxq - ox0) < 7u;
  const bool kxv1 = (unsigned)(kxq - ox1) < 7u;
#pragma unroll
  for (int mt = 0; mt < 4; mt++) {
#pragma unroll
    for (int r = 0; r < 4; r++) {
      int j = mt * 16 + kg * 4 + r;
      int oy = ((j >> 5) & 1) ? oy1 : oy0;
      bool kxv = ((j >> 2) & 1) ? kxv1 : kxv0;
      float l[4];
#pragma unroll
      for (int nt = 0; nt < 4; nt++) {
        int ky = 2 * nt + kyA;
        bool valid = kxv && ((unsigned)(ky - oy) < 7u);
        l[nt] = valid ? lg[mt][nt][r] * SCALE_ : -1e30f;
      }
      float mx = fmaxf(fmaxf(l[0], l[1]), fmaxf(l[2], l[3]));
#pragma unroll
      for (int off = 1; off < 16; off <<= 1) mx = fmaxf(mx, __shfl_xor(mx, off, 64));
      float e0 = __expf(l[0] - mx), e1 = __expf(l[1] - mx);
      float e2 = __expf(l[2] - mx), e3 = __expf(l[3] - mx);
      float ss = e0 + e1 + e2 + e3;
#pragma unroll
      for (int off = 1; off < 16; off <<= 1) ss += __shfl_xor(ss, off, 64);
      float inv = 1.f / ss;
      pk[mt][r][0] = (unsigned)f2bf(e0 * inv) | ((unsigned)f2bf(e1 * inv) << 16);
      pk[mt][r][1] = (unsigned)f2bf(e2 * inv) | ((unsigned)f2bf(e3 * inv) << 16);
    }
  }

  // ---- PV: O = 0.25 * sum_h P_h · V (sequential per-head buffer) ----
  f32x4 oacc[4][2];
#pragma unroll
  for (int a = 0; a < 4; a++)
#pragma unroll
    for (int n = 0; n < 2; n++) oacc[a][n] = (f32x4){0.f, 0.f, 0.f, 0.f};
#pragma unroll
  for (int hh = 0; hh < 4; hh++) {
    __syncthreads();
    if (w == hh) {
#pragma unroll
      for (int mt = 0; mt < 4; mt++)
#pragma unroll
        for (int r = 0; r < 4; r++) {
          int j = mt * 16 + kg * 4 + r;
          a1_l[j * 72 + lm]      = (unsigned short)(pk[mt][r][0] & 0xffffu);
          a1_l[j * 72 + 16 + lm] = (unsigned short)(pk[mt][r][0] >> 16);
          a1_l[j * 72 + 32 + lm] = (unsigned short)(pk[mt][r][1] & 0xffffu);
          a1_l[j * 72 + 48 + lm] = (unsigned short)(pk[mt][r][1] >> 16);
        }
    }
    __syncthreads();
#pragma unroll
    for (int kc = 0; kc < 2; kc++) {
      s8b pa[4], vb2[2];
#pragma unroll
      for (int mt = 0; mt < 4; mt++)
        pa[mt] = *(const s8b*)&a1_l[(mt * 16 + lm) * 72 + kc * 32 + kg * 8];
#pragma unroll
      for (int nt2 = 0; nt2 < 2; nt2++)
        vb2[nt2] = *(const s8b*)&v_l[(w * 32 + nt2 * 16 + lm) * 72 + kc * 32 + kg * 8];
#pragma unroll
      for (int mt = 0; mt < 4; mt++)
#pragma unroll
        for (int nt2 = 0; nt2 < 2; nt2++)
          oacc[mt][nt2] = __builtin_amdgcn_mfma_f32_16x16x32_bf16(pa[mt], vb2[nt2], oacc[mt][nt2], 0, 0, 0);
    }
  }
  __syncthreads();   // a1_l / v_l reads done; o_l overlays

  // ---- transposed output ----
#pragma unroll
  for (int mt = 0; mt < 4; mt++)
#pragma unroll
    for (int nt2 = 0; nt2 < 2; nt2++)
#pragma unroll
      for (int r = 0; r < 4; r++)
        o_l[(w * 32 + nt2 * 16 + lm) * 68 + mt * 16 + kg * 4 + r] = 0.25f * oacc[mt][nt2][r];
  __syncthreads();
  for (int i = tid; i < 2048; i += 256) {
    int c = i >> 4, rr = i & 15;
    int qy = rr >> 1, hx = rr & 1;
    float4 v = *(const float4*)&o_l[c * 68 + qy * 8 + hx * 4];
    *(float4*)&out[c * 16384 + (Y0 + qy) * 128 + X0 + hx * 4] = v;
  }
}

// ---------------------------------------------------------------------------
extern "C" void kernel_launch(void* const* d_in, const int* in_sizes, int n_in,
                              void* d_out, int out_size, void* d_ws, size_t ws_size,
                              hipStream_t stream) {
  const float* q_in    = (const float*)d_in[0];
  const float* k_in    = (const float*)d_in[1];
  const float* v_in    = (const float*)d_in[2];
  const float* conv_w  = (const float*)d_in[3];
  const float* normq_w = (const float*)d_in[4];
  const float* normk_w = (const float*)d_in[5];
  const float* qproj_w = (const float*)d_in[6];
  const float* qproj_b = (const float*)d_in[7];
  const float* kproj_w = (const float*)d_in[8];
  const float* kproj_b = (const float*)d_in[9];
  float* out = (float*)d_out;

  char* ws = (char*)d_ws;
  unsigned short* wb  = (unsigned short*)(ws);             // [9][4][128][32] bf16
  unsigned short* wnq = (unsigned short*)(ws + 294912);    // [128][128] bf16
  unsigned short* wnk = (unsigned short*)(ws + 327680);    // [128][128] bf16

  wpack_k<<<dim3(704), 256, 0, stream>>>(conv_w, qproj_w, normq_w, kproj_w, normk_w,
                                         wb, wnq, wnk);
  fused_k<<<dim3(256), 256, 0, stream>>>(q_in, k_in, v_in, wb, wnq, wnk,
                                         qproj_b, kproj_b, out);
}

// Round 6
// 120.674 us; speedup vs baseline: 1.1082x; 1.1082x over previous
//
#include <hip/hip_runtime.h>

#define EPS_ 1.1920928955078125e-07f
#define SCALE_ 0.17677669529663687f   // 1/sqrt(32)

typedef __attribute__((ext_vector_type(8))) short s8b;     // 8 bf16 (16B)
typedef __attribute__((ext_vector_type(4))) float f32x4;   // MFMA acc

static __device__ __forceinline__ unsigned short f2bf(float f) {
  unsigned int u = __float_as_uint(f);
  unsigned int r = (u + 0x7fffu + ((u >> 16) & 1u)) >> 16;   // RNE
  return (unsigned short)r;
}
static __device__ __forceinline__ int S_(int c) {        // NATTEN window start (cell grid)
  return (c < 3) ? 0 : ((c > 28) ? 25 : (c - 3));
}

// ---------------------------------------------------------------------------
// wpack: conv weights -> wb [9][4][128oc][32ic] bf16; wnq/wnk = proj_w*norm_w
// ---------------------------------------------------------------------------
__global__ __launch_bounds__(256) void wpack_k(
    const float* __restrict__ cw, const float* __restrict__ qw,
    const float* __restrict__ nqw, const float* __restrict__ kw,
    const float* __restrict__ nkw, unsigned short* __restrict__ wb,
    unsigned short* __restrict__ wnq, unsigned short* __restrict__ wnk) {
  int idx = blockIdx.x * 256 + threadIdx.x;
  if (idx < 147456) {
    int i32 = idx & 31, r = idx >> 5;
    int oc = r & 127, r2 = r >> 7;
    int kc = r2 & 3, t = r2 >> 2;
    wb[idx] = f2bf(cw[oc * 1152 + (kc * 32 + i32) * 9 + t]);
  } else if (idx < 163840) {
    int j = idx - 147456;
    wnq[j] = f2bf(qw[j] * nqw[j & 127]);
  } else if (idx < 180224) {
    int j = idx - 163840;
    wnk[j] = f2bf(kw[j] * nkw[j & 127]);
  }
}

// ---------------------------------------------------------------------------
// fused: per 8x8 output tile (grid 256, 512 threads = 8 waves):
// stage q halo/k/v from fp32 (k-rms folded into staging), k-proj, conv3x3
// implicit GEMM, q-rms+q-proj, QK^T (2 waves/head), masked softmax,
// PV (all heads accumulated), transposed output.
// LDS (65344B, phase-overlaid):
//   @0     in_l [100][136] bf16 (27200) -> qc_l [64][136] (17408)
//          -> a_l [4][64][72] (36864, after QK; spills over kx region)
//          -> o_l [128][68] f32 (34816, after PV)
//   @27200 kx_l [64][136] (17408)   (k staged, then projected in place)
//   @44608 v_l  [128][72] bf16 (18432)  (transposed)
//   @63040 red[512] f32 | @65088 rs[64] f32
// ---------------------------------------------------------------------------
__global__ __launch_bounds__(512) void fused_k(
    const float* __restrict__ q_in, const float* __restrict__ k_in,
    const float* __restrict__ v_in, const unsigned short* __restrict__ wb,
    const unsigned short* __restrict__ wnq, const unsigned short* __restrict__ wnk,
    const float* __restrict__ qbias, const float* __restrict__ kbias,
    float* __restrict__ out) {
  __shared__ __align__(16) char smem[65344];
  unsigned short* in_l = (unsigned short*)smem;
  unsigned short* qc_l = (unsigned short*)smem;
  unsigned short* a_l  = (unsigned short*)smem;
  float* o_l   = (float*)smem;
  unsigned short* kx_l = (unsigned short*)(smem + 27200);
  unsigned short* v_l  = (unsigned short*)(smem + 44608);
  float* red_l = (float*)(smem + 63040);
  float* rs_l  = (float*)(smem + 65088);

  const int tid = threadIdx.x;                 // 0..511
  const int CY = blockIdx.x >> 4, CX = blockIdx.x & 15;
  const int Y0 = CY * 8, X0 = CX * 8;
  const int w = tid >> 6, lane = tid & 63;
  const int lm = lane & 15, kg = lane >> 4;
  const int mg = w & 1, ng = w >> 1;           // conv/proj: 4 m-tiles, 1 n-tile
  const int h = w >> 1, mh = w & 1;            // QK: head, m-half

  const int sy0 = S_(2 * CY), sy1 = S_(2 * CY + 1);
  const int sx0 = S_(2 * CX), sx1 = S_(2 * CX + 1);
  const int kyb = min(sy0, 24), kxb = min(sx0, 24);
  const int oy0 = sy0 - kyb, oy1 = sy1 - kyb;
  const int ox0 = sx0 - kxb, ox1 = sx1 - kxb;

  // ---- stage q halo (zero-padded) ----
  for (int i = tid; i < 12800; i += 512) {
    int c = i / 100, r = i - c * 100;
    int ry = r / 10, rx = r - ry * 10;
    int gy = Y0 - 1 + ry, gx = X0 - 1 + rx;
    float v = 0.f;
    if ((unsigned)gy < 128u && (unsigned)gx < 128u) v = q_in[c * 16384 + gy * 128 + gx];
    in_l[r * 136 + c] = f2bf(v);
  }
  // ---- stage k (rms partials folded in) ----
  {
    const int j = tid & 63, cg = tid >> 3 >> 3;   // cg = tid>>6
    const int ky = j >> 3, kx = j & 7;
    const float* kp = &k_in[(kyb + ky) * 32 + kxb + kx];
    float s = 0.f;
#pragma unroll
    for (int it = 0; it < 16; it++) {
      int c = cg * 16 + it;
      float v = kp[c * 1024];
      s += v * v;
      kx_l[j * 136 + c] = f2bf(v);
    }
    red_l[j * 8 + cg] = s;
  }
  // ---- stage v transposed [c][key] ----
  {
    const int j = tid & 63, cg = tid >> 6;
    const int ky = j >> 3, kx = j & 7;
    const float* vp = &v_in[(kyb + ky) * 32 + kxb + kx];
#pragma unroll
    for (int it = 0; it < 16; it++) {
      int c = cg * 16 + it;
      v_l[c * 72 + j] = f2bf(vp[c * 1024]);
    }
  }
  __syncthreads();                                             // S1

  if (tid < 64) {
    float s = 0.f;
#pragma unroll
    for (int e = 0; e < 8; e++) s += red_l[tid * 8 + e];
    rs_l[tid] = rsqrtf(s * (1.f / 128.f) + EPS_);
  }
  __syncthreads();                                             // S2

  // ---- k proj: kp = kbias + rs*(wnk @ k) ----
  {
    f32x4 ka[4];
#pragma unroll
    for (int a = 0; a < 4; a++) ka[a] = (f32x4){0.f, 0.f, 0.f, 0.f};
#pragma unroll
    for (int kc = 0; kc < 4; kc++) {
      s8b af[4];
#pragma unroll
      for (int mt = 0; mt < 4; mt++)
        af[mt] = *(const s8b*)&wnk[((mg * 4 + mt) * 16 + lm) * 128 + kc * 32 + kg * 8];
      s8b bf = *(const s8b*)&kx_l[(ng * 16 + lm) * 136 + kc * 32 + kg * 8];
#pragma unroll
      for (int mt = 0; mt < 4; mt++)
        ka[mt] = __builtin_amdgcn_mfma_f32_16x16x32_bf16(af[mt], bf, ka[mt], 0, 0, 0);
    }
    __syncthreads();                                           // S3
    const int px = ng * 16 + lm;
    const float rs = rs_l[px];
#pragma unroll
    for (int mt = 0; mt < 4; mt++)
#pragma unroll
      for (int r = 0; r < 4; r++) {
        int c = (mg * 4 + mt) * 16 + kg * 4 + r;
        kx_l[px * 136 + c] = f2bf(kbias[c] + rs * ka[mt][r]);
      }
  }

  // ---- conv implicit GEMM: M=128 oc, N=64 px, K=1152 ----
  f32x4 acc[4];
#pragma unroll
  for (int a = 0; a < 4; a++) acc[a] = (f32x4){0.f, 0.f, 0.f, 0.f};
  const int pxc = ng * 16 + lm;
  const int qy = pxc >> 3, qx = pxc & 7;
#pragma unroll
  for (int t = 0; t < 9; t++) {
    const int dy = t / 3, dx = t - (t / 3) * 3;
#pragma unroll
    for (int kc = 0; kc < 4; kc++) {
      const unsigned short* wp = wb + (t * 4 + kc) * 4096;
      s8b af[4];
#pragma unroll
      for (int mt = 0; mt < 4; mt++)
        af[mt] = *(const s8b*)&wp[((mg * 4 + mt) * 16 + lm) * 32 + kg * 8];
      s8b bf = *(const s8b*)&in_l[((qy + dy) * 10 + qx + dx) * 136 + kc * 32 + kg * 8];
#pragma unroll
      for (int mt = 0; mt < 4; mt++)
        acc[mt] = __builtin_amdgcn_mfma_f32_16x16x32_bf16(af[mt], bf, acc[mt], 0, 0, 0);
    }
  }
  __syncthreads();                                             // S5 (in_l reads done)
#pragma unroll
  for (int mt = 0; mt < 4; mt++)
#pragma unroll
    for (int r = 0; r < 4; r++) {
      int c = (mg * 4 + mt) * 16 + kg * 4 + r;
      qc_l[pxc * 136 + c] = f2bf(acc[mt][r]);
    }
  __syncthreads();                                             // S6

  // ---- q rms ----
  {
    int px = tid >> 3, t8 = tid & 7;
    const unsigned short* row = &qc_l[px * 136 + t8 * 16];
    s8b v0 = *(const s8b*)row;
    s8b v1 = *(const s8b*)(row + 8);
    float s = 0.f;
#pragma unroll
    for (int e = 0; e < 8; e++) {
      float f0 = __uint_as_float(((unsigned)(unsigned short)v0[e]) << 16);
      float f1 = __uint_as_float(((unsigned)(unsigned short)v1[e]) << 16);
      s += f0 * f0 + f1 * f1;
    }
    red_l[px * 8 + t8] = s;
  }
  __syncthreads();                                             // S7
  if (tid < 64) {
    float s = 0.f;
#pragma unroll
    for (int e = 0; e < 8; e++) s += red_l[tid * 8 + e];
    rs_l[tid] = rsqrtf(s * (1.f / 128.f) + EPS_);
  }
  __syncthreads();                                             // S8

  // ---- q proj ----
  {
    f32x4 qa[4];
#pragma unroll
    for (int a = 0; a < 4; a++) qa[a] = (f32x4){0.f, 0.f, 0.f, 0.f};
#pragma unroll
    for (int kc = 0; kc < 4; kc++) {
      s8b af[4];
#pragma unroll
      for (int mt = 0; mt < 4; mt++)
        af[mt] = *(const s8b*)&wnq[((mg * 4 + mt) * 16 + lm) * 128 + kc * 32 + kg * 8];
      s8b bf = *(const s8b*)&qc_l[(ng * 16 + lm) * 136 + kc * 32 + kg * 8];
#pragma unroll
      for (int mt = 0; mt < 4; mt++)
        qa[mt] = __builtin_amdgcn_mfma_f32_16x16x32_bf16(af[mt], bf, qa[mt], 0, 0, 0);
    }
    __syncthreads();                                           // S9
    const int px = ng * 16 + lm;
    const float rs = rs_l[px];
#pragma unroll
    for (int mt = 0; mt < 4; mt++)
#pragma unroll
      for (int r = 0; r < 4; r++) {
        int c = (mg * 4 + mt) * 16 + kg * 4 + r;
        qc_l[px * 136 + c] = f2bf(qbias[c] + rs * qa[mt][r]);
      }
  }
  __syncthreads();                                             // S10

  // ---- QK^T: head h = w>>1, m-half mh = w&1 ----
  f32x4 lg[2][4];
  {
    s8b qa[2], kb[4];
#pragma unroll
    for (int mt = 0; mt < 2; mt++)
      qa[mt] = *(const s8b*)&qc_l[((mh * 2 + mt) * 16 + lm) * 136 + h * 32 + kg * 8];
#pragma unroll
    for (int nt = 0; nt < 4; nt++)
      kb[nt] = *(const s8b*)&kx_l[(nt * 16 + lm) * 136 + h * 32 + kg * 8];
#pragma unroll
    for (int mt = 0; mt < 2; mt++)
#pragma unroll
      for (int nt = 0; nt < 4; nt++)
        lg[mt][nt] = __builtin_amdgcn_mfma_f32_16x16x32_bf16(
            qa[mt], kb[nt], (f32x4){0.f, 0.f, 0.f, 0.f}, 0, 0, 0);
  }
  __syncthreads();                                             // S11 (qc/kx reads done)

  // ---- masked softmax, write P_h into a_l[4][64][72] ----
  {
    const int kyA = lm >> 3, kxq = lm & 7;
    const bool kxv0 = (unsigned)(kxq - ox0) < 7u;
    const bool kxv1 = (unsigned)(kxq - ox1) < 7u;
#pragma unroll
    for (int mt = 0; mt < 2; mt++) {
#pragma unroll
      for (int r = 0; r < 4; r++) {
        int j = (mh * 2 + mt) * 16 + kg * 4 + r;
        int oy = ((j >> 5) & 1) ? oy1 : oy0;
        bool kxv = ((j >> 2) & 1) ? kxv1 : kxv0;
        float l[4];
#pragma unroll
        for (int nt = 0; nt < 4; nt++) {
          int ky = 2 * nt + kyA;
          bool valid = kxv && ((unsigned)(ky - oy) < 7u);
          l[nt] = valid ? lg[mt][nt][r] * SCALE_ : -1e30f;
        }
        float mx = fmaxf(fmaxf(l[0], l[1]), fmaxf(l[2], l[3]));
#pragma unroll
        for (int off = 1; off < 16; off <<= 1) mx = fmaxf(mx, __shfl_xor(mx, off, 64));
        float e0 = __expf(l[0] - mx), e1 = __expf(l[1] - mx);
        float e2 = __expf(l[2] - mx), e3 = __expf(l[3] - mx);
        float ss = e0 + e1 + e2 + e3;
#pragma unroll
        for (int off = 1; off < 16; off <<= 1) ss += __shfl_xor(ss, off, 64);
        float inv = 1.f / ss;
        unsigned short* ap = &a_l[(h * 64 + j) * 72];
        ap[lm]      = f2bf(e0 * inv);
        ap[16 + lm] = f2bf(e1 * inv);
        ap[32 + lm] = f2bf(e2 * inv);
        ap[48 + lm] = f2bf(e3 * inv);
      }
    }
  }
  __syncthreads();                                             // S12

  // ---- PV: O = 0.25 * sum_h P_h · V ; wave = 16-channel band ----
  f32x4 oacc[4];
#pragma unroll
  for (int a = 0; a < 4; a++) oacc[a] = (f32x4){0.f, 0.f, 0.f, 0.f};
#pragma unroll
  for (int kc = 0; kc < 2; kc++) {
    s8b vb2 = *(const s8b*)&v_l[(w * 16 + lm) * 72 + kc * 32 + kg * 8];
#pragma unroll
    for (int hh = 0; hh < 4; hh++) {
#pragma unroll
      for (int mt = 0; mt < 4; mt++) {
        s8b pa = *(const s8b*)&a_l[(hh * 64 + mt * 16 + lm) * 72 + kc * 32 + kg * 8];
        oacc[mt] = __builtin_amdgcn_mfma_f32_16x16x32_bf16(pa, vb2, oacc[mt], 0, 0, 0);
      }
    }
  }
  __syncthreads();                                             // S13 (a_l/v_l reads done)

  // ---- transposed output ----
#pragma unroll
  for (int mt = 0; mt < 4; mt++)
#pragma unroll
    for (int r = 0; r < 4; r++)
      o_l[(w * 16 + lm) * 68 + mt * 16 + kg * 4 + r] = 0.25f * oacc[mt][r];
  __syncthreads();                                             // S14
  for (int i = tid; i < 2048; i += 512) {
    int c = i >> 4, rr = i & 15;
    int qyo = rr >> 1, hx = rr & 1;
    float4 v = *(const float4*)&o_l[c * 68 + qyo * 8 + hx * 4];
    *(float4*)&out[c * 16384 + (Y0 + qyo) * 128 + X0 + hx * 4] = v;
  }
}

// ---------------------------------------------------------------------------
extern "C" void kernel_launch(void* const* d_in, const int* in_sizes, int n_in,
                              void* d_out, int out_size, void* d_ws, size_t ws_size,
                              hipStream_t stream) {
  const float* q_in    = (const float*)d_in[0];
  const float* k_in    = (const float*)d_in[1];
  const float* v_in    = (const float*)d_in[2];
  const float* conv_w  = (const float*)d_in[3];
  const float* normq_w = (const float*)d_in[4];
  const float* normk_w = (const float*)d_in[5];
  const float* qproj_w = (const float*)d_in[6];
  const float* qproj_b = (const float*)d_in[7];
  const float* kproj_w = (const float*)d_in[8];
  const float* kproj_b = (const float*)d_in[9];
  float* out = (float*)d_out;

  char* ws = (char*)d_ws;
  unsigned short* wb  = (unsigned short*)(ws);             // [9][4][128][32] bf16
  unsigned short* wnq = (unsigned short*)(ws + 294912);    // [128][128] bf16
  unsigned short* wnk = (unsigned short*)(ws + 327680);    // [128][128] bf16

  wpack_k<<<dim3(704), 256, 0, stream>>>(conv_w, qproj_w, normq_w, kproj_w, normk_w,
                                         wb, wnq, wnk);
  fused_k<<<dim3(256), 512, 0, stream>>>(q_in, k_in, v_in, wb, wnq, wnk,
                                         qproj_b, kproj_b, out);
}

// Round 7
// 118.852 us; speedup vs baseline: 1.1252x; 1.0153x over previous
//
#include <hip/hip_runtime.h>

#define EPS_ 1.1920928955078125e-07f
#define SCALE_ 0.17677669529663687f   // 1/sqrt(32)

typedef __attribute__((ext_vector_type(8))) short s8b;     // 8 bf16 (16B)
typedef __attribute__((ext_vector_type(4))) float f32x4;   // MFMA acc

static __device__ __forceinline__ unsigned short f2bf(float f) {
  unsigned int u = __float_as_uint(f);
  unsigned int r = (u + 0x7fffu + ((u >> 16) & 1u)) >> 16;   // RNE
  return (unsigned short)r;
}
static __device__ __forceinline__ float b2fs(short h) {
  return __uint_as_float(((unsigned int)(unsigned short)h) << 16);
}
static __device__ __forceinline__ int S_(int c) {        // NATTEN window start (cell grid)
  return (c < 3) ? 0 : ((c > 28) ? 25 : (c - 3));
}

// ---------------------------------------------------------------------------
// prep (grid 921):
//  [0,256)   q fp32 NCHW -> bf16 NHWC padded qb [130][130][128]
//  [256,265) zero qb halo border
//  [265,281) k-side: rms + kproj MFMA -> kpb [1024][128] bf16 NHWC (64 px/blk)
//  [281,921) weight packs: wb [9][4][128oc][32ic], wnq [128][128]
// ---------------------------------------------------------------------------
__global__ __launch_bounds__(256) void prep_k(
    const float* __restrict__ q_in, const float* __restrict__ k_in,
    const float* __restrict__ conv_w, const float* __restrict__ normq_w,
    const float* __restrict__ normk_w, const float* __restrict__ qproj_w,
    const float* __restrict__ kproj_w, const float* __restrict__ kbias,
    unsigned short* __restrict__ qb, unsigned short* __restrict__ kpb,
    unsigned short* __restrict__ wb, unsigned short* __restrict__ wnq) {
  __shared__ __align__(16) char smem[53504];
  unsigned short* t_l = (unsigned short*)smem;             // [64][136]
  unsigned short* x_l = (unsigned short*)smem;             // [64][136] (k-proj)
  unsigned short* wnk_l = (unsigned short*)(smem + 17408); // [128][136]
  float* red_l = (float*)(smem + 52224);                   // [256]
  float* rs_l  = (float*)(smem + 53248);                   // [64]
  const int b = blockIdx.x, tid = threadIdx.x;
  const int w = tid >> 6, lane = tid & 63;
  const int lm = lane & 15, kg = lane >> 4;

  if (b < 256) {
    const int px0 = b * 64;
    for (int i = tid; i < 2048; i += 256) {
      int c = i >> 4, f = i & 15;
      float4 v = *(const float4*)&q_in[c * 16384 + px0 + f * 4];
      t_l[(f * 4 + 0) * 136 + c] = f2bf(v.x);
      t_l[(f * 4 + 1) * 136 + c] = f2bf(v.y);
      t_l[(f * 4 + 2) * 136 + c] = f2bf(v.z);
      t_l[(f * 4 + 3) * 136 + c] = f2bf(v.w);
    }
    __syncthreads();
    for (int i = tid; i < 1024; i += 256) {
      int p = i >> 4, s = i & 15;
      int px = px0 + p;
      int opx = px + 2 * (px >> 7) + 131;   // (y+1)*130 + (x+1)
      *(s8b*)&qb[opx * 128 + s * 8] = *(const s8b*)&t_l[p * 136 + s * 8];
    }
  } else if (b < 265) {
    int gid = (b - 256) * 256 + tid;   // 2304 threads
    s8b z = {0, 0, 0, 0, 0, 0, 0, 0};
    for (int j = gid; j < 2080; j += 2304) {
      *(s8b*)&qb[j * 8] = z;
      *(s8b*)&qb[129 * 130 * 128 + j * 8] = z;
    }
    for (int j = gid; j < 2048; j += 2304) {
      int r = (j >> 4) + 1, s = j & 15;
      *(s8b*)&qb[(r * 130) * 128 + s * 8] = z;
      *(s8b*)&qb[(r * 130 + 129) * 128 + s * 8] = z;
    }
  } else if (b < 281) {
    // ------- k-side rms + proj, 64 px -------
    const int px0 = (b - 265) * 64;
    for (int i = tid; i < 2048; i += 256) {   // stage k transposed bf16
      int c = i >> 4, f = i & 15;
      float4 v = *(const float4*)&k_in[c * 1024 + px0 + f * 4];
      x_l[(f * 4 + 0) * 136 + c] = f2bf(v.x);
      x_l[(f * 4 + 1) * 136 + c] = f2bf(v.y);
      x_l[(f * 4 + 2) * 136 + c] = f2bf(v.z);
      x_l[(f * 4 + 3) * 136 + c] = f2bf(v.w);
    }
    for (int i = tid; i < 16384; i += 256) {  // wnk = kproj_w * normk
      int o = i >> 7, c = i & 127;
      wnk_l[o * 136 + c] = f2bf(kproj_w[i] * normk_w[c]);
    }
    __syncthreads();
    {
      int px = tid >> 2, t4 = tid & 3;
      float ssum = 0.f;
#pragma unroll
      for (int j = 0; j < 4; j++) {
        s8b v = *(const s8b*)&x_l[px * 136 + t4 * 32 + j * 8];
#pragma unroll
        for (int e = 0; e < 8; e++) { float f = b2fs(v[e]); ssum += f * f; }
      }
      red_l[px * 4 + t4] = ssum;
    }
    __syncthreads();
    if (tid < 64)
      rs_l[tid] = rsqrtf((red_l[4 * tid] + red_l[4 * tid + 1] + red_l[4 * tid + 2] +
                          red_l[4 * tid + 3]) * (1.f / 128.f) + EPS_);
    __syncthreads();
    f32x4 acc[2][4];
#pragma unroll
    for (int a = 0; a < 2; a++)
#pragma unroll
      for (int n = 0; n < 4; n++) acc[a][n] = (f32x4){0.f, 0.f, 0.f, 0.f};
#pragma unroll
    for (int kc = 0; kc < 4; kc++) {
      s8b a0 = *(const s8b*)&wnk_l[(2 * w * 16 + lm) * 136 + kc * 32 + kg * 8];
      s8b a1 = *(const s8b*)&wnk_l[((2 * w + 1) * 16 + lm) * 136 + kc * 32 + kg * 8];
#pragma unroll
      for (int nt = 0; nt < 4; nt++) {
        s8b bf = *(const s8b*)&x_l[(nt * 16 + lm) * 136 + kc * 32 + kg * 8];
        acc[0][nt] = __builtin_amdgcn_mfma_f32_16x16x32_bf16(a0, bf, acc[0][nt], 0, 0, 0);
        acc[1][nt] = __builtin_amdgcn_mfma_f32_16x16x32_bf16(a1, bf, acc[1][nt], 0, 0, 0);
      }
    }
    __syncthreads();
#pragma unroll
    for (int mi = 0; mi < 2; mi++)
#pragma unroll
      for (int nt = 0; nt < 4; nt++)
#pragma unroll
        for (int r = 0; r < 4; r++) {
          int px = nt * 16 + lm, c = (2 * w + mi) * 16 + kg * 4 + r;
          x_l[px * 136 + c] = f2bf(kbias[c] + rs_l[px] * acc[mi][nt][r]);
        }
    __syncthreads();
    for (int i = tid; i < 1024; i += 256) {
      int px = i >> 4, s = i & 15;
      *(s8b*)&kpb[(px0 + px) * 128 + s * 8] = *(const s8b*)&x_l[px * 136 + s * 8];
    }
  } else {
    int idx = (b - 281) * 256 + tid;   // < 163840
    if (idx < 147456) {
      int i32 = idx & 31, r = idx >> 5;
      int oc = r & 127, r2 = r >> 7;
      int kc = r2 & 3, t = r2 >> 2;
      wb[idx] = f2bf(conv_w[oc * 1152 + (kc * 32 + i32) * 9 + t]);
    } else {
      int j = idx - 147456;
      wnq[j] = f2bf(qproj_w[j] * normq_w[j & 127]);
    }
  }
}

// ---------------------------------------------------------------------------
// fused (grid 256, 512 thr = 8 waves): per 8x8 output tile.
// Stages packed bf16 qb/kpb (16B vec loads) + v from fp32; conv3x3 implicit
// GEMM (A from global, L2-hot), q-rms+qproj, QK^T (2 waves/head), masked
// softmax, PV (all heads), transposed output.
// LDS (65344B, phase-overlaid):
//   @0     in_l [100][136] bf16 (27200) -> qc_l [64][136] (17408)
//          -> a_l [4][64][72] (36864, after QK) -> o_l [128][68] f32 (34816)
//   @27200 kx_l [64][136] (17408)   (projected k window)
//   @44608 v_l  [128][72] bf16 (18432)  (transposed)
//   @63040 red[512] f32 | @65088 rs[64] f32
// ---------------------------------------------------------------------------
__global__ __launch_bounds__(512) void fused_k(
    const unsigned short* __restrict__ qb, const unsigned short* __restrict__ kpb,
    const float* __restrict__ v_in, const unsigned short* __restrict__ wb,
    const unsigned short* __restrict__ wnq, const float* __restrict__ qbias,
    float* __restrict__ out) {
  __shared__ __align__(16) char smem[65344];
  unsigned short* in_l = (unsigned short*)smem;
  unsigned short* qc_l = (unsigned short*)smem;
  unsigned short* a_l  = (unsigned short*)smem;
  float* o_l   = (float*)smem;
  unsigned short* kx_l = (unsigned short*)(smem + 27200);
  unsigned short* v_l  = (unsigned short*)(smem + 44608);
  float* red_l = (float*)(smem + 63040);
  float* rs_l  = (float*)(smem + 65088);

  const int tid = threadIdx.x;                 // 0..511
  const int CY = blockIdx.x >> 4, CX = blockIdx.x & 15;
  const int Y0 = CY * 8, X0 = CX * 8;
  const int w = tid >> 6, lane = tid & 63;
  const int lm = lane & 15, kg = lane >> 4;
  const int mg = w & 1, ng = w >> 1;           // conv/proj: 4 m-tiles, 1 n-tile
  const int h = w >> 1, mh = w & 1;            // QK: head, m-half

  const int sy0 = S_(2 * CY), sy1 = S_(2 * CY + 1);
  const int sx0 = S_(2 * CX), sx1 = S_(2 * CX + 1);
  const int kyb = min(sy0, 24), kxb = min(sx0, 24);
  const int oy0 = sy0 - kyb, oy1 = sy1 - kyb;
  const int ox0 = sx0 - kxb, ox1 = sx1 - kxb;

  // ---- stage q halo [100][136] from padded qb (pure 16B vec) ----
  for (int i = tid; i < 1600; i += 512) {
    int s = i & 15, r = i >> 4;
    int ry = r / 10, rx = r - ry * 10;
    *(s8b*)&in_l[r * 136 + s * 8] =
        *(const s8b*)&qb[((Y0 + ry) * 130 + X0 + rx) * 128 + s * 8];
  }
  // ---- stage projected k window [64][136] (16B vec) ----
  for (int i = tid; i < 1024; i += 512) {
    int j = i >> 4, s = i & 15;
    int ky = j >> 3, kx = j & 7;
    *(s8b*)&kx_l[j * 136 + s * 8] =
        *(const s8b*)&kpb[((kyb + ky) * 32 + kxb + kx) * 128 + s * 8];
  }
  // ---- stage v transposed [c][key] from fp32 ----
  {
    const int j = tid & 63, cg = tid >> 6;
    const int ky = j >> 3, kx = j & 7;
    const float* vp = &v_in[(kyb + ky) * 32 + kxb + kx];
#pragma unroll
    for (int it = 0; it < 16; it++) {
      int c = cg * 16 + it;
      v_l[c * 72 + j] = f2bf(vp[c * 1024]);
    }
  }
  __syncthreads();                                             // S1

  // ---- conv implicit GEMM: M=128 oc, N=64 px, K=1152 ----
  f32x4 acc[4];
#pragma unroll
  for (int a = 0; a < 4; a++) acc[a] = (f32x4){0.f, 0.f, 0.f, 0.f};
  const int pxc = ng * 16 + lm;
  const int qy = pxc >> 3, qx = pxc & 7;
#pragma unroll
  for (int t = 0; t < 9; t++) {
    const int dy = t / 3, dx = t - (t / 3) * 3;
#pragma unroll
    for (int kc = 0; kc < 4; kc++) {
      const unsigned short* wp = wb + (t * 4 + kc) * 4096;
      s8b af[4];
#pragma unroll
      for (int mt = 0; mt < 4; mt++)
        af[mt] = *(const s8b*)&wp[((mg * 4 + mt) * 16 + lm) * 32 + kg * 8];
      s8b bf = *(const s8b*)&in_l[((qy + dy) * 10 + qx + dx) * 136 + kc * 32 + kg * 8];
#pragma unroll
      for (int mt = 0; mt < 4; mt++)
        acc[mt] = __builtin_amdgcn_mfma_f32_16x16x32_bf16(af[mt], bf, acc[mt], 0, 0, 0);
    }
  }
  __syncthreads();                                             // S2 (in_l reads done)
#pragma unroll
  for (int mt = 0; mt < 4; mt++)
#pragma unroll
    for (int r = 0; r < 4; r++) {
      int c = (mg * 4 + mt) * 16 + kg * 4 + r;
      qc_l[pxc * 136 + c] = f2bf(acc[mt][r]);
    }
  __syncthreads();                                             // S3

  // ---- q rms ----
  {
    int px = tid >> 3, t8 = tid & 7;
    const unsigned short* row = &qc_l[px * 136 + t8 * 16];
    s8b v0 = *(const s8b*)row;
    s8b v1 = *(const s8b*)(row + 8);
    float s = 0.f;
#pragma unroll
    for (int e = 0; e < 8; e++) {
      float f0 = b2fs(v0[e]), f1 = b2fs(v1[e]);
      s += f0 * f0 + f1 * f1;
    }
    red_l[px * 8 + t8] = s;
  }
  __syncthreads();                                             // S4
  if (tid < 64) {
    float s = 0.f;
#pragma unroll
    for (int e = 0; e < 8; e++) s += red_l[tid * 8 + e];
    rs_l[tid] = rsqrtf(s * (1.f / 128.f) + EPS_);
  }
  __syncthreads();                                             // S5

  // ---- q proj ----
  {
    f32x4 qa[4];
#pragma unroll
    for (int a = 0; a < 4; a++) qa[a] = (f32x4){0.f, 0.f, 0.f, 0.f};
#pragma unroll
    for (int kc = 0; kc < 4; kc++) {
      s8b af[4];
#pragma unroll
      for (int mt = 0; mt < 4; mt++)
        af[mt] = *(const s8b*)&wnq[((mg * 4 + mt) * 16 + lm) * 128 + kc * 32 + kg * 8];
      s8b bf = *(const s8b*)&qc_l[pxc * 136 + kc * 32 + kg * 8];
#pragma unroll
      for (int mt = 0; mt < 4; mt++)
        qa[mt] = __builtin_amdgcn_mfma_f32_16x16x32_bf16(af[mt], bf, qa[mt], 0, 0, 0);
    }
    __syncthreads();                                           // S6 (qc reads done)
    const float rs = rs_l[pxc];
#pragma unroll
    for (int mt = 0; mt < 4; mt++)
#pragma unroll
      for (int r = 0; r < 4; r++) {
        int c = (mg * 4 + mt) * 16 + kg * 4 + r;
        qc_l[pxc * 136 + c] = f2bf(qbias[c] + rs * qa[mt][r]);
      }
  }
  __syncthreads();                                             // S7

  // ---- QK^T: head h = w>>1, m-half mh = w&1 ----
  f32x4 lg[2][4];
  {
    s8b qa[2], kb[4];
#pragma unroll
    for (int mt = 0; mt < 2; mt++)
      qa[mt] = *(const s8b*)&qc_l[((mh * 2 + mt) * 16 + lm) * 136 + h * 32 + kg * 8];
#pragma unroll
    for (int nt = 0; nt < 4; nt++)
      kb[nt] = *(const s8b*)&kx_l[(nt * 16 + lm) * 136 + h * 32 + kg * 8];
#pragma unroll
    for (int mt = 0; mt < 2; mt++)
#pragma unroll
      for (int nt = 0; nt < 4; nt++)
        lg[mt][nt] = __builtin_amdgcn_mfma_f32_16x16x32_bf16(
            qa[mt], kb[nt], (f32x4){0.f, 0.f, 0.f, 0.f}, 0, 0, 0);
  }
  __syncthreads();                                             // S8 (qc/kx reads done)

  // ---- masked softmax, write P_h into a_l[4][64][72] ----
  {
    const int kyA = lm >> 3, kxq = lm & 7;
    const bool kxv0 = (unsigned)(kxq - ox0) < 7u;
    const bool kxv1 = (unsigned)(kxq - ox1) < 7u;
#pragma unroll
    for (int mt = 0; mt < 2; mt++) {
#pragma unroll
      for (int r = 0; r < 4; r++) {
        int j = (mh * 2 + mt) * 16 + kg * 4 + r;
        int oy = ((j >> 5) & 1) ? oy1 : oy0;
        bool kxv = ((j >> 2) & 1) ? kxv1 : kxv0;
        float l[4];
#pragma unroll
        for (int nt = 0; nt < 4; nt++) {
          int ky = 2 * nt + kyA;
          bool valid = kxv && ((unsigned)(ky - oy) < 7u);
          l[nt] = valid ? lg[mt][nt][r] * SCALE_ : -1e30f;
        }
        float mx = fmaxf(fmaxf(l[0], l[1]), fmaxf(l[2], l[3]));
#pragma unroll
        for (int off = 1; off < 16; off <<= 1) mx = fmaxf(mx, __shfl_xor(mx, off, 64));
        float e0 = __expf(l[0] - mx), e1 = __expf(l[1] - mx);
        float e2 = __expf(l[2] - mx), e3 = __expf(l[3] - mx);
        float ss = e0 + e1 + e2 + e3;
#pragma unroll
        for (int off = 1; off < 16; off <<= 1) ss += __shfl_xor(ss, off, 64);
        float inv = 1.f / ss;
        unsigned short* ap = &a_l[(h * 64 + j) * 72];
        ap[lm]      = f2bf(e0 * inv);
        ap[16 + lm] = f2bf(e1 * inv);
        ap[32 + lm] = f2bf(e2 * inv);
        ap[48 + lm] = f2bf(e3 * inv);
      }
    }
  }
  __syncthreads();                                             // S9

  // ---- PV: O = 0.25 * sum_h P_h · V ; wave = 16-channel band ----
  f32x4 oacc[4];
#pragma unroll
  for (int a = 0; a < 4; a++) oacc[a] = (f32x4){0.f, 0.f, 0.f, 0.f};
#pragma unroll
  for (int kc = 0; kc < 2; kc++) {
    s8b vb2 = *(const s8b*)&v_l[(w * 16 + lm) * 72 + kc * 32 + kg * 8];
#pragma unroll
    for (int hh = 0; hh < 4; hh++) {
#pragma unroll
      for (int mt = 0; mt < 4; mt++) {
        s8b pa = *(const s8b*)&a_l[(hh * 64 + mt * 16 + lm) * 72 + kc * 32 + kg * 8];
        oacc[mt] = __builtin_amdgcn_mfma_f32_16x16x32_bf16(pa, vb2, oacc[mt], 0, 0, 0);
      }
    }
  }
  __syncthreads();                                             // S10 (a_l/v_l reads done)

  // ---- transposed output ----
#pragma unroll
  for (int mt = 0; mt < 4; mt++)
#pragma unroll
    for (int r = 0; r < 4; r++)
      o_l[(w * 16 + lm) * 68 + mt * 16 + kg * 4 + r] = 0.25f * oacc[mt][r];
  __syncthreads();                                             // S11
  for (int i = tid; i < 2048; i += 512) {
    int c = i >> 4, rr = i & 15;
    int qyo = rr >> 1, hx = rr & 1;
    float4 v = *(const float4*)&o_l[c * 68 + qyo * 8 + hx * 4];
    *(float4*)&out[c * 16384 + (Y0 + qyo) * 128 + X0 + hx * 4] = v;
  }
}

// ---------------------------------------------------------------------------
extern "C" void kernel_launch(void* const* d_in, const int* in_sizes, int n_in,
                              void* d_out, int out_size, void* d_ws, size_t ws_size,
                              hipStream_t stream) {
  const float* q_in    = (const float*)d_in[0];
  const float* k_in    = (const float*)d_in[1];
  const float* v_in    = (const float*)d_in[2];
  const float* conv_w  = (const float*)d_in[3];
  const float* normq_w = (const float*)d_in[4];
  const float* normk_w = (const float*)d_in[5];
  const float* qproj_w = (const float*)d_in[6];
  const float* qproj_b = (const float*)d_in[7];
  const float* kproj_w = (const float*)d_in[8];
  const float* kproj_b = (const float*)d_in[9];
  float* out = (float*)d_out;

  char* ws = (char*)d_ws;
  unsigned short* qb  = (unsigned short*)(ws);             // [130][130][128] bf16
  unsigned short* kpb = (unsigned short*)(ws + 4326400);   // [1024][128] bf16
  unsigned short* wb  = (unsigned short*)(ws + 4588544);   // [9][4][128][32] bf16
  unsigned short* wnq = (unsigned short*)(ws + 4883456);   // [128][128] bf16

  prep_k<<<dim3(921), 256, 0, stream>>>(q_in, k_in, conv_w, normq_w, normk_w,
                                        qproj_w, kproj_w, kproj_b,
                                        qb, kpb, wb, wnq);
  fused_k<<<dim3(256), 512, 0, stream>>>(qb, kpb, v_in, wb, wnq, qproj_b, out);
}